// Round 1
// baseline (14670.615 us; speedup 1.0000x reference)
//
#include <hip/hip_runtime.h>
#include <math.h>

// LSTMDecoder: VOCAB=32000, EMB=512, HID=512, LAYERS=2, BATCH=32, SEQ=64
// Strategy (round 1, fp32-exact to keep argmax trajectory locked to reference):
//  prep (8 nodes): transpose fcW->fcWT[k][v], Wih/Whh->W2T[l][k][j] (k-major),
//                  bias2 = bih+bhh, states transposed to [k][b], zero slots/ctr.
//  per step (3 nodes): klstm(l=0), klstm(l=1), kfc(+argmax atomicMax + out write)
// All GEMM inner loops: coalesced weight load (lanes over output dim) x 32
// wave-uniform activation loads (scalar pipe) -> 32 independent v_fmac_f32.

#define BB   32
#define EMBD 512
#define HIDD 512
#define VV   32000
#define SS   64
#define GJ   2048          // 4*HID
#define OST  (SS*VV)       // out stride per batch

__device__ __forceinline__ float sigf(float x){ return 1.0f/(1.0f + expf(-x)); }
__device__ __forceinline__ unsigned keyOf(float f){
  unsigned u = __float_as_uint(f);
  return (u & 0x80000000u) ? ~u : (u | 0x80000000u);   // monotone float->uint
}

// generic 32x32 tiled transpose: dst[c*dstLd + r] = src[r*C + c]
__global__ void ktran(const float* __restrict__ src, float* __restrict__ dst,
                      int R, int C, int dstLd)
{
  __shared__ float t[32][33];
  int c0 = blockIdx.x*32, r0 = blockIdx.y*32;
  int tx = threadIdx.x & 31, ty = threadIdx.x >> 5;
  #pragma unroll
  for (int i=0;i<4;i++) t[ty+i*8][tx] = src[(size_t)(r0+ty+i*8)*C + (c0+tx)];
  __syncthreads();
  #pragma unroll
  for (int i=0;i<4;i++) dst[(size_t)(c0+ty+i*8)*dstLd + (r0+tx)] = t[tx][ty+i*8];
}

__global__ void kbias(const float* __restrict__ bih, const float* __restrict__ bhh,
                      float* __restrict__ bias2){
  int i = blockIdx.x*256 + threadIdx.x;
  if (i < 2*GJ) bias2[i] = bih[i] + bhh[i];
}

// x0T[k][b] = input_seq[b][0][k];  hT/cT parity0: [l][u][b] = h_encode[l][b][u]
__global__ void kinit(const float* __restrict__ iseq, const float* __restrict__ he,
                      const float* __restrict__ ce, float* __restrict__ x0T,
                      float* __restrict__ hT, float* __restrict__ cT)
{
  int tid = blockIdx.x*256 + threadIdx.x;
  if (tid < 16384){
    int k = tid>>5, b = tid&31;
    x0T[tid] = iseq[(size_t)b*(SS*EMBD) + k];
  } else if (tid < 49152){
    int t2 = tid - 16384;
    int l = t2>>14, r = t2&16383, u = r>>5, b = r&31;
    hT[t2] = he[(size_t)(l*BB + b)*HIDD + u];
  } else if (tid < 81920){
    int t2 = tid - 49152;
    int l = t2>>14, r = t2&16383, u = r>>5, b = r&31;
    cT[t2] = ce[(size_t)(l*BB + b)*HIDD + u];
  }
}

// One LSTM layer. grid=256: jt=bx&31 (64-wide j tile), ko=bx>>5 (128-wide k chunk
// of K=1024=[x(512);h(512)]). block=256=4 waves (kc: 32-wide k subchunk).
// Partials -> part[ko][b][j]; last block per unit-group (ticket ctr) does the
// cell update (sigmoid/tanh) and writes hdst/cdst ([u][b], parity-flipped).
__global__ __launch_bounds__(256) void klstm(
    const float* __restrict__ W2T, const float* __restrict__ bias2,
    const float* __restrict__ xsrc, const unsigned long long* __restrict__ slots_prev,
    const float* __restrict__ emb,
    const float* __restrict__ hsrc, const float* __restrict__ csrc,
    float* __restrict__ hdst, float* __restrict__ cdst,
    float* __restrict__ part, unsigned* __restrict__ ctr, int use_emb)
{
  __shared__ float xg[128*36];      // gathered emb rows, [k_local][b], pad 36
  __shared__ float red[4*32*64];    // [kc][b][lane]
  __shared__ int isLast;
  int bx = blockIdx.x;
  int jt = bx & 31, ko = bx >> 5;
  int tid = threadIdx.x, lane = tid & 63, kc = tid >> 6;
  int j = jt*64 + lane;
  int kbase = ko*128 + kc*32;

  if (use_emb && ko < 4){
    // x = emb[argmax(prev)]: gather this block's 128-k slice for all 32 b
    int gb = tid & 31, kt = tid >> 5;          // 32 b x 8 kt x 16 k
    unsigned long long pk = slots_prev[gb];
    unsigned idx = 0xFFFFFFFFu - (unsigned)(pk & 0xFFFFFFFFull);
    const float* row = emb + (size_t)idx*EMBD + ko*128;
    #pragma unroll
    for (int i=0;i<16;i++){
      int kl = kt*16 + i;
      xg[kl*36 + gb] = row[kl];
    }
  }
  __syncthreads();

  float acc[BB];
  #pragma unroll
  for (int b=0;b<BB;b++) acc[b] = 0.f;

  const float* wp = W2T + (size_t)kbase*GJ + j;
  if (ko >= 4){                                  // h-recurrent half, [u][b] global
    const float* base = hsrc + (size_t)(kbase - 512)*BB;
    for (int kk=0;kk<32;kk++){
      float w = wp[(size_t)kk*GJ];
      const float* xr = base + kk*BB;            // wave-uniform -> scalar loads
      #pragma unroll
      for (int b=0;b<BB;b++) acc[b] = fmaf(xr[b], w, acc[b]);
    }
  } else if (!use_emb){                          // x from x0T or previous layer hT
    const float* base = xsrc + (size_t)kbase*BB;
    for (int kk=0;kk<32;kk++){
      float w = wp[(size_t)kk*GJ];
      const float* xr = base + kk*BB;
      #pragma unroll
      for (int b=0;b<BB;b++) acc[b] = fmaf(xr[b], w, acc[b]);
    }
  } else {                                       // x from LDS-gathered emb rows
    for (int kk=0;kk<32;kk++){
      float w = wp[(size_t)kk*GJ];
      const float* xr = &xg[(kc*32 + kk)*36];
      #pragma unroll
      for (int bq=0;bq<8;bq++){
        float4 xa = *(const float4*)(xr + bq*4);
        acc[bq*4+0] = fmaf(xa.x, w, acc[bq*4+0]);
        acc[bq*4+1] = fmaf(xa.y, w, acc[bq*4+1]);
        acc[bq*4+2] = fmaf(xa.z, w, acc[bq*4+2]);
        acc[bq*4+3] = fmaf(xa.w, w, acc[bq*4+3]);
      }
    }
  }

  #pragma unroll
  for (int b=0;b<BB;b++) red[(kc*32+b)*64 + lane] = acc[b];
  __syncthreads();

  int jl = tid & 63, bg = tid >> 6;
  #pragma unroll
  for (int i=0;i<8;i++){
    int b = bg*8 + i;
    float v = red[b*64+jl] + red[(32+b)*64+jl] + red[(64+b)*64+jl] + red[(96+b)*64+jl];
    part[((size_t)ko*32 + b)*GJ + jt*64 + jl] = v;   // coalesced over j
  }
  __threadfence();            // release partials device-wide
  __syncthreads();
  int ug = jt & 7;            // unit group: units ug*64..+63 <- jt in {ug,ug+8,ug+16,ug+24}
  if (tid == 0) isLast = (atomicAdd(&ctr[ug], 1u) == 31u);
  __syncthreads();
  if (!isLast) return;

  if (tid == 0) ctr[ug] = 0;  // re-arm for next use (visible at next kernel launch)
  __threadfence();            // acquire
  const int u0 = ug*64;
  for (int i=0;i<8;i++){
    int cid = i*256 + tid;
    int u = cid >> 5, b = cid & 31;
    int uu = u0 + u;
    float gi=0.f, gf=0.f, gg=0.f, go=0.f;
    #pragma unroll
    for (int k2=0;k2<8;k2++){
      const volatile float* pp = (const volatile float*)(part + ((size_t)k2*32 + b)*GJ);
      gi += pp[uu];
      gf += pp[512  + uu];
      gg += pp[1024 + uu];
      go += pp[1536 + uu];
    }
    gi += bias2[uu]; gf += bias2[512+uu]; gg += bias2[1024+uu]; go += bias2[1536+uu];
    float co = csrc[uu*BB + b];
    float cn = sigf(gf)*co + sigf(gi)*tanhf(gg);
    float hn = sigf(go)*tanhf(cn);
    cdst[uu*BB + b] = cn;
    hdst[uu*BB + b] = hn;
  }
}

// FC + argmax. grid=500 (64-wide v tiles), block=256=4 waves (kc: 128-wide k).
// Writes logits to out[b][s][v]; block-local argmax -> packed u64 atomicMax into
// slots_cur; block 0 re-zeros slots_next for step s+1.
__global__ __launch_bounds__(256) void kfc(
    const float* __restrict__ fcWT, const float* __restrict__ fcb,
    const float* __restrict__ h1T, float* __restrict__ out, int s,
    unsigned long long* __restrict__ slots_cur,
    unsigned long long* __restrict__ slots_next)
{
  __shared__ float red[4*32*64];
  __shared__ float fin[32*65];
  int vt = blockIdx.x;
  int tid = threadIdx.x, lane = tid & 63, kc = tid >> 6;
  int v = vt*64 + lane;

  float acc[BB];
  #pragma unroll
  for (int b=0;b<BB;b++) acc[b] = 0.f;

  const float* wp = fcWT + (size_t)(kc*128)*VV + v;
  const float* hb = h1T + kc*128*BB;
  for (int kk=0;kk<128;kk++){
    float w = wp[(size_t)kk*VV];                 // coalesced over v
    const float* xr = hb + kk*BB;                // wave-uniform -> scalar loads
    #pragma unroll
    for (int b=0;b<BB;b++) acc[b] = fmaf(xr[b], w, acc[b]);
  }
  #pragma unroll
  for (int b=0;b<BB;b++) red[(kc*32+b)*64 + lane] = acc[b];
  __syncthreads();

  int jl = tid & 63, bg = tid >> 6;
  #pragma unroll
  for (int i=0;i<8;i++){
    int b = bg*8 + i;
    float val = red[b*64+jl] + red[(32+b)*64+jl] + red[(64+b)*64+jl] + red[(96+b)*64+jl]
              + fcb[vt*64 + jl];
    out[(size_t)b*OST + (size_t)s*VV + vt*64 + jl] = val;
    fin[b*65 + jl] = val;
  }
  __syncthreads();

  if (tid < 32){
    int b = tid;
    float best = fin[b*65]; int bv = 0;
    for (int w2=1; w2<64; w2++){                 // ascending scan: first max wins
      float f = fin[b*65 + w2];
      if (f > best){ best = f; bv = w2; }
    }
    unsigned long long pk = ((unsigned long long)keyOf(best) << 32)
                          | (unsigned long long)(0xFFFFFFFFu - (unsigned)(vt*64 + bv));
    unsigned long long cur = slots_cur[b];       // guard read (optimization only)
    if (pk > cur) atomicMax(slots_cur + b, pk);
  }
  if (vt == 0 && tid >= 64 && tid < 96) slots_next[tid - 64] = 0ull;
}

extern "C" void kernel_launch(void* const* d_in, const int* in_sizes, int n_in,
                              void* d_out, int out_size, void* d_ws, size_t ws_size,
                              hipStream_t stream)
{
  const float* input_seq = (const float*)d_in[0];
  const float* h_enc     = (const float*)d_in[1];
  const float* c_enc     = (const float*)d_in[2];
  const float* Wih       = (const float*)d_in[3];
  const float* Whh       = (const float*)d_in[4];
  const float* bih       = (const float*)d_in[5];
  const float* bhh       = (const float*)d_in[6];
  const float* fcW       = (const float*)d_in[7];
  const float* fcb       = (const float*)d_in[8];
  const float* emb       = (const float*)d_in[9];
  float* out = (float*)d_out;

  // workspace carve-out (~86 MB total)
  char* ws = (char*)d_ws;
  size_t off = 0;
  auto alloc = [&](size_t bytes)->void*{
    void* p = ws + off; off += (bytes + 255) & ~(size_t)255; return p;
  };
  float* fcWT  = (float*)alloc((size_t)512*VV*4);        // [k][v]
  float* W2T   = (float*)alloc((size_t)2*1024*GJ*4);     // [l][k][j]
  float* bias2 = (float*)alloc((size_t)2*GJ*4);
  float* x0T   = (float*)alloc((size_t)512*BB*4);        // [k][b]
  float* hT    = (float*)alloc((size_t)2*2*512*BB*4);    // [parity][l][u][b]
  float* cT    = (float*)alloc((size_t)2*2*512*BB*4);
  float* part  = (float*)alloc((size_t)8*BB*GJ*4);       // [ko][b][j]
  unsigned long long* slots = (unsigned long long*)alloc(2*BB*8); // [parity][b]
  unsigned* ctr = (unsigned*)alloc(8*4);

  hipMemsetAsync(slots, 0, 2*BB*8, stream);
  hipMemsetAsync(ctr,   0, 8*4,    stream);

  dim3 tb(256);
  // fcW (32000x512) -> fcWT (512x32000)
  ktran<<<dim3(16,1000), tb, 0, stream>>>(fcW, fcWT, VV, 512, VV);
  // per layer: W2T rows 0..511 = WihT, rows 512..1023 = WhhT  (ld = 2048)
  ktran<<<dim3(16,64), tb, 0, stream>>>(Wih,            W2T,                         GJ, 512, GJ);
  ktran<<<dim3(16,64), tb, 0, stream>>>(Whh,            W2T + (size_t)512*GJ,        GJ, 512, GJ);
  ktran<<<dim3(16,64), tb, 0, stream>>>(Wih + (size_t)GJ*512, W2T + (size_t)1024*GJ, GJ, 512, GJ);
  ktran<<<dim3(16,64), tb, 0, stream>>>(Whh + (size_t)GJ*512, W2T + (size_t)1024*GJ + (size_t)512*GJ, GJ, 512, GJ);
  kbias<<<16, tb, 0, stream>>>(bih, bhh, bias2);
  kinit<<<320, tb, 0, stream>>>(input_seq, h_enc, c_enc, x0T, hT, cT);

  const size_t LSZ = 512*BB;   // one [u][b] state plane
  for (int s=0; s<SS; s++){
    int p = s & 1, q = p ^ 1;
    float* h0s = hT + (size_t)(p*2+0)*LSZ;  float* h0d = hT + (size_t)(q*2+0)*LSZ;
    float* h1s = hT + (size_t)(p*2+1)*LSZ;  float* h1d = hT + (size_t)(q*2+1)*LSZ;
    float* c0s = cT + (size_t)(p*2+0)*LSZ;  float* c0d = cT + (size_t)(q*2+0)*LSZ;
    float* c1s = cT + (size_t)(p*2+1)*LSZ;  float* c1d = cT + (size_t)(q*2+1)*LSZ;

    // layer 0: x = (s==0 ? input_seq[:,0,:] : emb[argmax(prev)])
    klstm<<<256, tb, 0, stream>>>(W2T, bias2,
        (s==0) ? x0T : nullptr,
        (s>0) ? (slots + ((s-1)&1)*BB) : nullptr,
        emb, h0s, c0s, h0d, c0d, part, ctr, (s>0) ? 1 : 0);
    // layer 1: x = h0(new)
    klstm<<<256, tb, 0, stream>>>(W2T + (size_t)1024*GJ, bias2 + GJ,
        h0d, nullptr, emb, h1s, c1s, h1d, c1d, part, ctr, 0);
    // FC + argmax; also zero next-parity slots for step s+1
    kfc<<<500, tb, 0, stream>>>(fcWT, fcb, h1d, out, s,
        slots + (s&1)*BB, slots + ((s+1)&1)*BB);
  }
}

// Round 2
// 8483.729 us; speedup vs baseline: 1.7293x; 1.7293x over previous
//
#include <hip/hip_runtime.h>
#include <math.h>

// LSTMDecoder: VOCAB=32000, EMB=512, HID=512, LAYERS=2, BATCH=32, SEQ=64
// Round 2: FMA-bound inner loops.
//  kfc:  250 blocks x 256 thr; lane owns 2 cols (float2 weight loads, 512B/wave),
//        h via wave-uniform global float4 broadcasts (1 txn/instr, L2-hot 64KB),
//        4-way k-split reduced in LDS (2-phase, 50KB total).
//  klstm: 256 blocks; block stages its 128x32 activation chunk in LDS (16KB),
//        inner loop = same-address LDS broadcast float4 reads (conflict-free);
//        part[ko][j][b] so partial stores AND finisher loads are coalesced.

#define BB   32
#define EMBD 512
#define HIDD 512
#define VV   32000
#define SS   64
#define GJ   2048          // 4*HID
#define OST  (SS*VV)       // out stride per batch

__device__ __forceinline__ float sigf(float x){ return 1.0f/(1.0f + expf(-x)); }
__device__ __forceinline__ unsigned keyOf(float f){
  unsigned u = __float_as_uint(f);
  return (u & 0x80000000u) ? ~u : (u | 0x80000000u);   // monotone float->uint
}

// generic 32x32 tiled transpose: dst[c*dstLd + r] = src[r*C + c]
__global__ void ktran(const float* __restrict__ src, float* __restrict__ dst,
                      int R, int C, int dstLd)
{
  __shared__ float t[32][33];
  int c0 = blockIdx.x*32, r0 = blockIdx.y*32;
  int tx = threadIdx.x & 31, ty = threadIdx.x >> 5;
  #pragma unroll
  for (int i=0;i<4;i++) t[ty+i*8][tx] = src[(size_t)(r0+ty+i*8)*C + (c0+tx)];
  __syncthreads();
  #pragma unroll
  for (int i=0;i<4;i++) dst[(size_t)(c0+ty+i*8)*dstLd + (r0+tx)] = t[tx][ty+i*8];
}

__global__ void kbias(const float* __restrict__ bih, const float* __restrict__ bhh,
                      float* __restrict__ bias2){
  int i = blockIdx.x*256 + threadIdx.x;
  if (i < 2*GJ) bias2[i] = bih[i] + bhh[i];
}

// x0T[k][b] = input_seq[b][0][k];  hT/cT parity0: [l][u][b] = h_encode[l][b][u]
__global__ void kinit(const float* __restrict__ iseq, const float* __restrict__ he,
                      const float* __restrict__ ce, float* __restrict__ x0T,
                      float* __restrict__ hT, float* __restrict__ cT)
{
  int tid = blockIdx.x*256 + threadIdx.x;
  if (tid < 16384){
    int k = tid>>5, b = tid&31;
    x0T[tid] = iseq[(size_t)b*(SS*EMBD) + k];
  } else if (tid < 49152){
    int t2 = tid - 16384;
    int l = t2>>14, r = t2&16383, u = r>>5, b = r&31;
    hT[t2] = he[(size_t)(l*BB + b)*HIDD + u];
  } else if (tid < 81920){
    int t2 = tid - 49152;
    int l = t2>>14, r = t2&16383, u = r>>5, b = r&31;
    cT[t2] = ce[(size_t)(l*BB + b)*HIDD + u];
  }
}

// One LSTM layer. grid=256: jt=bx&31 (64-wide j tile), ko=bx>>5 (128-wide k chunk
// of K=1024=[x(512);h(512)]). block=256=4 waves (kc: 32-wide k subchunk).
// Activation chunk staged in LDS; inner reads are wave-uniform broadcasts.
// Partials -> part[ko][j][b] (coalesced both ways); ticket finisher does cell.
__global__ __launch_bounds__(256) void klstm(
    const float* __restrict__ W2T, const float* __restrict__ bias2,
    const float* __restrict__ xsrc, const unsigned long long* __restrict__ slots_prev,
    const float* __restrict__ emb,
    const float* __restrict__ hsrc, const float* __restrict__ csrc,
    float* __restrict__ hdst, float* __restrict__ cdst,
    float* __restrict__ part, unsigned* __restrict__ ctr, int use_emb)
{
  __shared__ float xg[128*32];      // block's 128-k x 32-b activation chunk
  __shared__ float red[4*32*65];    // [kc*32+b][j], pad 65 vs bank conflicts
  __shared__ int isLast;
  int bx = blockIdx.x;
  int jt = bx & 31, ko = bx >> 5;
  int tid = threadIdx.x, lane = tid & 63, kc = tid >> 6;
  int j = jt*64 + lane;

  // ---- stage activation chunk into LDS ----
  if (ko >= 4){                                   // recurrent half: h chunk
    const float* base = hsrc + (size_t)(ko-4)*128*BB;
    #pragma unroll
    for (int i=0;i<4;i++)
      *(float4*)&xg[(i*256+tid)*4] = *(const float4*)(base + (size_t)(i*256+tid)*4);
  } else if (!use_emb){                           // x chunk (x0T or prev-layer hT)
    const float* base = xsrc + (size_t)ko*128*BB;
    #pragma unroll
    for (int i=0;i<4;i++)
      *(float4*)&xg[(i*256+tid)*4] = *(const float4*)(base + (size_t)(i*256+tid)*4);
  } else {                                        // x = emb[argmax(prev)] gather
    int gb = tid & 31, kt = tid >> 5;             // 32 b x 8 kt (16 k each)
    unsigned long long pk = slots_prev[gb];
    unsigned idx = 0xFFFFFFFFu - (unsigned)(pk & 0xFFFFFFFFull);
    const float* row = emb + (size_t)idx*EMBD + ko*128 + kt*16;
    #pragma unroll
    for (int q=0;q<4;q++){
      float4 r4 = *(const float4*)(row + q*4);
      xg[(kt*16+q*4+0)*32 + gb] = r4.x;
      xg[(kt*16+q*4+1)*32 + gb] = r4.y;
      xg[(kt*16+q*4+2)*32 + gb] = r4.z;
      xg[(kt*16+q*4+3)*32 + gb] = r4.w;
    }
  }
  __syncthreads();

  // ---- GEMM: 32 k-iters, LDS broadcast activations ----
  float acc[BB];
  #pragma unroll
  for (int b=0;b<BB;b++) acc[b] = 0.f;

  const float* wp = W2T + (size_t)(ko*128 + kc*32)*GJ + j;
  const float* xb = &xg[(kc*32)*32];
  for (int kk=0;kk<32;kk++){
    float w = wp[(size_t)kk*GJ];                  // coalesced over j
    const float* xr = xb + kk*32;                 // same addr all lanes: broadcast
    #pragma unroll
    for (int bq=0;bq<8;bq++){
      float4 xa = *(const float4*)(xr + bq*4);
      acc[bq*4+0] = fmaf(xa.x, w, acc[bq*4+0]);
      acc[bq*4+1] = fmaf(xa.y, w, acc[bq*4+1]);
      acc[bq*4+2] = fmaf(xa.z, w, acc[bq*4+2]);
      acc[bq*4+3] = fmaf(xa.w, w, acc[bq*4+3]);
    }
  }

  #pragma unroll
  for (int b=0;b<BB;b++) red[(kc*32+b)*65 + lane] = acc[b];
  __syncthreads();

  // ---- reduce 4 kc partials, store part[ko][j][b] fully coalesced ----
  #pragma unroll
  for (int i=0;i<8;i++){
    int idx = i*256 + tid, jl = idx >> 5, b2 = idx & 31;
    float v = red[(0*32+b2)*65 + jl] + red[(1*32+b2)*65 + jl]
            + red[(2*32+b2)*65 + jl] + red[(3*32+b2)*65 + jl];
    part[((size_t)ko*GJ + jt*64 + jl)*BB + b2] = v;
  }
  __threadfence();            // release partials device-wide
  __syncthreads();
  int ug = jt & 7;            // unit group: 64 units <- jt in {ug,ug+8,ug+16,ug+24}
  if (tid == 0) isLast = (atomicAdd(&ctr[ug], 1u) == 31u);
  __syncthreads();
  if (!isLast) return;

  if (tid == 0) ctr[ug] = 0;  // re-arm for next launch
  __threadfence();            // acquire (kernel also starts w/ acquire next launch)
  const int u0 = ug*64;
  for (int i=0;i<8;i++){
    int cid = i*256 + tid;
    int u = cid >> 5, b2 = cid & 31;
    int uu = u0 + u;
    float gi=0.f, gf=0.f, gg=0.f, go=0.f;
    #pragma unroll
    for (int k2=0;k2<8;k2++){
      const float* pp = part + (size_t)k2*GJ*BB;  // coalesced: b on lanes
      gi += pp[(size_t)(0*512+uu)*BB + b2];
      gf += pp[(size_t)(1*512+uu)*BB + b2];
      gg += pp[(size_t)(2*512+uu)*BB + b2];
      go += pp[(size_t)(3*512+uu)*BB + b2];
    }
    gi += bias2[uu]; gf += bias2[512+uu]; gg += bias2[1024+uu]; go += bias2[1536+uu];
    float co = csrc[uu*BB + b2];
    float cn = sigf(gf)*co + sigf(gi)*tanhf(gg);
    float hn = sigf(go)*tanhf(cn);
    cdst[uu*BB + b2] = cn;
    hdst[uu*BB + b2] = hn;
  }
}

// FC + argmax. grid=250 (128-col tiles), block=256=4 waves.
// Lane owns 2 cols (float2 weights); kc=tid>>6 is a 128-k split; h broadcast via
// wave-uniform global float4 (1 txn/instr). 2-phase LDS reduction, then argmax.
__global__ __launch_bounds__(256) void kfc(
    const float* __restrict__ fcWT, const float* __restrict__ fcb,
    const float* __restrict__ h1T, float* __restrict__ out, int s,
    unsigned long long* __restrict__ slots_cur,
    unsigned long long* __restrict__ slots_next)
{
  __shared__ float part[2][128*33];   // [pb][c][b], pad 33
  __shared__ float fin[32*129];       // [b][c], pad 129
  int bx = blockIdx.x;
  int tid = threadIdx.x, lane = tid & 63, kc = tid >> 6;
  int c0 = lane*2;
  int v0 = bx*128 + c0;

  float acc0[BB], acc1[BB];
  #pragma unroll
  for (int b=0;b<BB;b++){ acc0[b] = 0.f; acc1[b] = 0.f; }

  const float2* wp = (const float2*)(fcWT + (size_t)(kc*128)*VV) + (v0 >> 1);
  const float*  hb = h1T + kc*128*BB;
  for (int kk=0;kk<128;kk++){
    float2 w = wp[(size_t)kk*(VV/2)];             // 512B/wave, coalesced over v
    const float* xr = hb + kk*BB;                 // wave-uniform: 1 txn per float4
    #pragma unroll
    for (int bq=0;bq<8;bq++){
      float4 xa = *(const float4*)(xr + bq*4);
      acc0[bq*4+0] = fmaf(xa.x, w.x, acc0[bq*4+0]);
      acc1[bq*4+0] = fmaf(xa.x, w.y, acc1[bq*4+0]);
      acc0[bq*4+1] = fmaf(xa.y, w.x, acc0[bq*4+1]);
      acc1[bq*4+1] = fmaf(xa.y, w.y, acc1[bq*4+1]);
      acc0[bq*4+2] = fmaf(xa.z, w.x, acc0[bq*4+2]);
      acc1[bq*4+2] = fmaf(xa.z, w.y, acc1[bq*4+2]);
      acc0[bq*4+3] = fmaf(xa.w, w.x, acc0[bq*4+3]);
      acc1[bq*4+3] = fmaf(xa.w, w.y, acc1[bq*4+3]);
    }
  }

  // 2-phase k-reduction in LDS (kc0/1 write, kc2/3 add)
  if (kc < 2){
    float* p = &part[kc][0];
    #pragma unroll
    for (int b=0;b<BB;b++){ p[(c0+0)*33 + b] = acc0[b]; p[(c0+1)*33 + b] = acc1[b]; }
  }
  __syncthreads();
  if (kc >= 2){
    float* p = &part[kc-2][0];
    #pragma unroll
    for (int b=0;b<BB;b++){ p[(c0+0)*33 + b] += acc0[b]; p[(c0+1)*33 + b] += acc1[b]; }
  }
  __syncthreads();

  // epilogue: bias, out write (coalesced over v), fin for argmax
  #pragma unroll
  for (int i=0;i<16;i++){
    int cl = (tid & 63) + 64*(i & 1);
    int b  = (tid >> 6) + 4*(i >> 1);
    float val = part[0][cl*33 + b] + part[1][cl*33 + b] + fcb[bx*128 + cl];
    out[(size_t)b*OST + (size_t)s*VV + bx*128 + cl] = val;
    fin[b*129 + cl] = val;
  }
  __syncthreads();

  if (tid < 32){
    int b = tid;
    float best = fin[b*129]; int bv = 0;
    for (int c=1; c<128; c++){                    // ascending: first max wins
      float f = fin[b*129 + c];
      if (f > best){ best = f; bv = c; }
    }
    unsigned long long pk = ((unsigned long long)keyOf(best) << 32)
                          | (unsigned long long)(0xFFFFFFFFu - (unsigned)(bx*128 + bv));
    unsigned long long cur = slots_cur[b];        // guard read (perf only; safe)
    if (pk > cur) atomicMax(slots_cur + b, pk);
  }
  if (bx == 0 && tid >= 64 && tid < 96) slots_next[tid - 64] = 0ull;
}

extern "C" void kernel_launch(void* const* d_in, const int* in_sizes, int n_in,
                              void* d_out, int out_size, void* d_ws, size_t ws_size,
                              hipStream_t stream)
{
  const float* input_seq = (const float*)d_in[0];
  const float* h_enc     = (const float*)d_in[1];
  const float* c_enc     = (const float*)d_in[2];
  const float* Wih       = (const float*)d_in[3];
  const float* Whh       = (const float*)d_in[4];
  const float* bih       = (const float*)d_in[5];
  const float* bhh       = (const float*)d_in[6];
  const float* fcW       = (const float*)d_in[7];
  const float* fcb       = (const float*)d_in[8];
  const float* emb       = (const float*)d_in[9];
  float* out = (float*)d_out;

  char* ws = (char*)d_ws;
  size_t off = 0;
  auto alloc = [&](size_t bytes)->void*{
    void* p = ws + off; off += (bytes + 255) & ~(size_t)255; return p;
  };
  float* fcWT  = (float*)alloc((size_t)512*VV*4);        // [k][v]
  float* W2T   = (float*)alloc((size_t)2*1024*GJ*4);     // [l][k][j]
  float* bias2 = (float*)alloc((size_t)2*GJ*4);
  float* x0T   = (float*)alloc((size_t)512*BB*4);        // [k][b]
  float* hT    = (float*)alloc((size_t)2*2*512*BB*4);    // [parity][l][u][b]
  float* cT    = (float*)alloc((size_t)2*2*512*BB*4);
  float* partL0= (float*)alloc((size_t)8*GJ*BB*4);       // [ko][j][b]
  float* partL1= (float*)alloc((size_t)8*GJ*BB*4);
  unsigned long long* slots = (unsigned long long*)alloc(2*BB*8); // [parity][b]
  unsigned* ctr = (unsigned*)alloc(16*4);                // [layer][ug]

  hipMemsetAsync(slots, 0, 2*BB*8, stream);
  hipMemsetAsync(ctr,   0, 16*4,   stream);

  dim3 tb(256);
  ktran<<<dim3(16,1000), tb, 0, stream>>>(fcW, fcWT, VV, 512, VV);
  ktran<<<dim3(16,64), tb, 0, stream>>>(Wih,            W2T,                         GJ, 512, GJ);
  ktran<<<dim3(16,64), tb, 0, stream>>>(Whh,            W2T + (size_t)512*GJ,        GJ, 512, GJ);
  ktran<<<dim3(16,64), tb, 0, stream>>>(Wih + (size_t)GJ*512, W2T + (size_t)1024*GJ, GJ, 512, GJ);
  ktran<<<dim3(16,64), tb, 0, stream>>>(Whh + (size_t)GJ*512, W2T + (size_t)1024*GJ + (size_t)512*GJ, GJ, 512, GJ);
  kbias<<<16, tb, 0, stream>>>(bih, bhh, bias2);
  kinit<<<320, tb, 0, stream>>>(input_seq, h_enc, c_enc, x0T, hT, cT);

  const size_t LSZ = 512*BB;
  for (int s=0; s<SS; s++){
    int p = s & 1, q = p ^ 1;
    float* h0s = hT + (size_t)(p*2+0)*LSZ;  float* h0d = hT + (size_t)(q*2+0)*LSZ;
    float* h1s = hT + (size_t)(p*2+1)*LSZ;  float* h1d = hT + (size_t)(q*2+1)*LSZ;
    float* c0s = cT + (size_t)(p*2+0)*LSZ;  float* c0d = cT + (size_t)(q*2+0)*LSZ;
    float* c1s = cT + (size_t)(p*2+1)*LSZ;  float* c1d = cT + (size_t)(q*2+1)*LSZ;

    klstm<<<256, tb, 0, stream>>>(W2T, bias2,
        (s==0) ? x0T : nullptr,
        (s>0) ? (slots + ((s-1)&1)*BB) : nullptr,
        emb, h0s, c0s, h0d, c0d, partL0, ctr, (s>0) ? 1 : 0);
    klstm<<<256, tb, 0, stream>>>(W2T + (size_t)1024*GJ, bias2 + GJ,
        h0d, nullptr, emb, h1s, c1s, h1d, c1d, partL1, ctr + 8, 0);
    kfc<<<250, tb, 0, stream>>>(fcWT, fcb, h1d, out, s,
        slots + (s&1)*BB, slots + ((s+1)&1)*BB);
  }
}